// Round 5
// baseline (245.776 us; speedup 1.0000x reference)
//
#include <hip/hip_runtime.h>

// GNN surrogate — f16 MFMA, 2 waves per batch (block=128), 10 KB shared slab.
// Wave w owns node rows 64w..64w+63 (g-tiles 4w..4w+3). Only 3 cross-wave
// barriers per layer (L-write, af2-read, H'-write hazards on the bufH/bufL
// overlay). Biases ride in the MFMA C-operand (exact). Folds (exact):
// v[j]=mean_i adj[i,j] absorbs layer-3 aggregation; u=W2[2]@W_ro,
// c=(b2[2]·W_ro)*sum(v)+b_ro absorbs the readout.

typedef _Float16 f16;
typedef __attribute__((ext_vector_type(8))) _Float16 half8;
typedef __attribute__((ext_vector_type(4))) _Float16 half4;
typedef __attribute__((ext_vector_type(2))) _Float16 half2;
typedef __attribute__((ext_vector_type(2))) __fp16 fp16x2;   // cvt_pkrtz native type
typedef __attribute__((ext_vector_type(4))) float f32x4;

namespace {
constexpr int N = 128, H = 32;
// ws byte layout
constexpr int WS_ADJF = 0;       // f16 [128][128] adj row-major      (32768 B)
constexpr int WS_W1T  = 32768;   // f16 [3][32][32] W1^T [fout][fin]  (6144 B)
constexpr int WS_W2T  = 38912;   // f16 [3][32][32] W2^T [fout][fmid] (6144 B)
constexpr int WS_V    = 45056;   // f32 [128] v[j] = mean_i adj[i][j]
constexpr int WS_U    = 45568;   // f32 [32]  u[k] = sum_c W2[2][k][c]*W_ro[c]
constexpr int WS_C    = 45696;   // f32 [1]
constexpr int RS = 40;    // bufH row stride in f16 (80 B)
constexpr int LS = 136;   // bufL row stride in f16 (272 B), overlaid on bufH
}

static __device__ __forceinline__ half2 pk2(float a, float b) {
  union { fp16x2 r; half2 v; } u;
  u.r = __builtin_amdgcn_cvt_pkrtz(a, b);
  return u.v;
}
static __device__ __forceinline__ half4 pk4(float a, float b, float c, float d) {
  union { half4 v; fp16x2 h[2]; } u;
  u.h[0] = __builtin_amdgcn_cvt_pkrtz(a, b);
  u.h[1] = __builtin_amdgcn_cvt_pkrtz(c, d);
  return u.v;
}

__global__ void prep(const float* __restrict__ adj,
                     const float* __restrict__ W1,
                     const float* __restrict__ W2,
                     const float* __restrict__ b2,
                     const float* __restrict__ W_ro,
                     const float* __restrict__ b_ro,
                     char* __restrict__ ws) {
  const int tid = threadIdx.x;
  const int gid = blockIdx.x * 256 + tid;
  f16* adjf = (f16*)(ws + WS_ADJF);
  f16* w1t  = (f16*)(ws + WS_W1T);
  f16* w2t  = (f16*)(ws + WS_W2T);
  float* v  = (float*)(ws + WS_V);
  float* u  = (float*)(ws + WS_U);
  float* cp = (float*)(ws + WS_C);

  for (int idx = gid; idx < N * N; idx += 2048) adjf[idx] = (f16)adj[idx];
  for (int idx = gid; idx < 3 * H * H; idx += 2048) {
    const int l = idx / (H * H), rem = idx % (H * H);
    const int fo = rem / H, fi = rem % H;
    w1t[idx] = (f16)W1[l * H * H + fi * H + fo];
    w2t[idx] = (f16)W2[l * H * H + fi * H + fo];
  }
  if (blockIdx.x == 0) {
    __shared__ float sred[N];
    if (tid < N) {
      float s = 0.f;
      for (int i = 0; i < N; ++i) s += adj[i * N + tid];
      v[tid] = s * (1.0f / N);
      sred[tid] = s * (1.0f / N);
    }
    if (tid < H) {
      float s = 0.f;
      for (int c = 0; c < H; ++c) s += W2[2 * H * H + tid * H + c] * W_ro[c];
      u[tid] = s;
    }
    __syncthreads();
    if (tid == 0) {
      float c2r = 0.f;
      for (int k = 0; k < H; ++k) c2r += b2[2 * H + k] * W_ro[k];
      float S = 0.f;
      for (int j = 0; j < N; ++j) S += sred[j];
      cp[0] = c2r * S + b_ro[0];
    }
  }
}

__global__ __launch_bounds__(128, 7)
void gnn_mfma(const float* __restrict__ x,
              const float* __restrict__ W_lift,
              const float* __restrict__ b_lift,
              const float* __restrict__ b1,
              const float* __restrict__ b2,
              const char* __restrict__ ws,
              float* __restrict__ out) {
  __shared__ f16 slab[N * RS];   // 10240 B -> up to 16 blocks/CU by LDS

  const f16* adjf = (const f16*)(ws + WS_ADJF);
  const f16* w1t  = (const f16*)(ws + WS_W1T);
  const f16* w2t  = (const f16*)(ws + WS_W2T);
  const float* v  = (const float*)(ws + WS_V);
  const float* u  = (const float*)(ws + WS_U);
  const float* cp = (const float*)(ws + WS_C);

  const int tid  = threadIdx.x;
  const int wave = tid >> 6;    // 0/1: owns nodes 64*wave .. 64*wave+63
  const int lane = tid & 63;
  const int lrow = lane & 15;
  const int quad = lane >> 4;
  const int b    = blockIdx.x;

  const f32x4 zero = {0.f, 0.f, 0.f, 0.f};

  // ---- lift: one node per lane -> bufH row (4x ds_write_b128) ----
  {
    const int node = wave * 64 + lane;
    const float* xr = x + (size_t)b * (N * 3) + node * 3;
    const float x0 = xr[0], x1 = xr[1], x2 = xr[2];
    f16* row = slab + node * RS;
#pragma unroll
    for (int kk = 0; kk < 4; ++kk) {
      float f[8];
#pragma unroll
      for (int k = 0; k < 8; ++k) {
        const int kc = kk * 8 + k;
        f[k] = fmaf(x0, W_lift[kc],
               fmaf(x1, W_lift[H + kc],
               fmaf(x2, W_lift[2 * H + kc], b_lift[kc])));
      }
      union { half8 v; half2 h[4]; } p;
      p.h[0] = pk2(f[0], f[1]); p.h[1] = pk2(f[2], f[3]);
      p.h[2] = pk2(f[4], f[5]); p.h[3] = pk2(f[6], f[7]);
      *(half8*)(row + kk * 8) = p.v;
    }
  }

  // ---- layers 0,1 ----
  for (int l = 0; l < 2; ++l) {
    // Stage A: T = relu(W1^T·H^T + b1), in place on own rows. Bias = C-init.
    {
      const f16* w1l = w1t + l * H * H;
      const half8 a0 = *(const half8*)(w1l + lrow * H + quad * 8);
      const half8 a1 = *(const half8*)(w1l + (16 + lrow) * H + quad * 8);
      const f32x4 bi0 = *(const f32x4*)(b1 + l * H + quad * 4);
      const f32x4 bi1 = *(const f32x4*)(b1 + l * H + 16 + quad * 4);
#pragma unroll
      for (int g = 0; g < 4; ++g) {
        f16* row = slab + ((wave * 4 + g) * 16 + lrow) * RS;
        const half8 bf = *(const half8*)(row + quad * 8);
        const f32x4 c0 = __builtin_amdgcn_mfma_f32_16x16x32_f16(a0, bf, bi0, 0, 0, 0);
        const f32x4 c1 = __builtin_amdgcn_mfma_f32_16x16x32_f16(a1, bf, bi1, 0, 0, 0);
        *(half4*)(row + quad * 4) =
            pk4(fmaxf(c0[0], 0.f), fmaxf(c0[1], 0.f), fmaxf(c0[2], 0.f), fmaxf(c0[3], 0.f));
        *(half4*)(row + 16 + quad * 4) =
            pk4(fmaxf(c1[0], 0.f), fmaxf(c1[1], 0.f), fmaxf(c1[2], 0.f), fmaxf(c1[3], 0.f));
      }
    }

    // Stage B: L = T·W2 + b2 -> bufL (L^T[fout][node]). Preload own af, then
    // barrier (other wave's T rows alias our L-write range).
    {
      const f16* w2l = w2t + l * H * H;
      const half8 wb0 = *(const half8*)(w2l + lrow * H + quad * 8);
      const half8 wb1 = *(const half8*)(w2l + (16 + lrow) * H + quad * 8);
      const float bs0 = b2[l * H + lrow];
      const float bs1 = b2[l * H + 16 + lrow];
      const f32x4 bi0 = {bs0, bs0, bs0, bs0};
      const f32x4 bi1 = {bs1, bs1, bs1, bs1};
      half8 af[4];
#pragma unroll
      for (int m = 0; m < 4; ++m)
        af[m] = *(const half8*)(slab + ((wave * 4 + m) * 16 + lrow) * RS + quad * 8);
      __syncthreads();   // B1: all T reads done before any L write
#pragma unroll
      for (int m = 0; m < 4; ++m) {
        const f32x4 d0 = __builtin_amdgcn_mfma_f32_16x16x32_f16(af[m], wb0, bi0, 0, 0, 0);
        const f32x4 d1 = __builtin_amdgcn_mfma_f32_16x16x32_f16(af[m], wb1, bi1, 0, 0, 0);
        const int ncol = (wave * 4 + m) * 16 + quad * 4;
        *(half4*)(slab + lrow * LS + ncol)        = pk4(d0[0], d0[1], d0[2], d0[3]);
        *(half4*)(slab + (16 + lrow) * LS + ncol) = pk4(d1[0], d1[1], d1[2], d1[3]);
      }
    }

    // Stage C: H' = adj·L on own rows. af2 needs BOTH waves' L -> C1; H'
    // writes clobber bufL -> C2 after preload.
    {
      __syncthreads();   // C1: all L writes visible
      half8 af2[2][4];
#pragma unroll
      for (int mt = 0; mt < 2; ++mt)
#pragma unroll
        for (int kt = 0; kt < 4; ++kt)
          af2[mt][kt] = *(const half8*)(slab + (mt * 16 + lrow) * LS + kt * 32 + quad * 8);
      __syncthreads();   // C2: af2 preloads done before H' writes
#pragma unroll
      for (int g = 0; g < 4; ++g) {
        const int gi = wave * 4 + g;
        f32x4 h0 = zero, h1 = zero;
#pragma unroll
        for (int kt = 0; kt < 4; ++kt) {
          const half8 bf = *(const half8*)(adjf + (gi * 16 + lrow) * N + kt * 32 + quad * 8);
          h0 = __builtin_amdgcn_mfma_f32_16x16x32_f16(af2[0][kt], bf, h0, 0, 0, 0);
          h1 = __builtin_amdgcn_mfma_f32_16x16x32_f16(af2[1][kt], bf, h1, 0, 0, 0);
        }
        f16* row = slab + (gi * 16 + lrow) * RS;
        *(half4*)(row + quad * 4)      = pk4(h0[0], h0[1], h0[2], h0[3]);
        *(half4*)(row + 16 + quad * 4) = pk4(h1[0], h1[1], h1[2], h1[3]);
      }
    }
  }

  // ---- layer 2 + folded readout (own rows; no barrier needed) ----
  {
    const f16* w1l = w1t + 2 * H * H;
    const half8 a0 = *(const half8*)(w1l + lrow * H + quad * 8);
    const half8 a1 = *(const half8*)(w1l + (16 + lrow) * H + quad * 8);
    const f32x4 bi0 = *(const f32x4*)(b1 + 2 * H + quad * 4);
    const f32x4 bi1 = *(const f32x4*)(b1 + 2 * H + 16 + quad * 4);
    const float4 u0 = *(const float4*)(u + quad * 4);
    const float4 u1 = *(const float4*)(u + 16 + quad * 4);
    float partial = 0.f;
#pragma unroll
    for (int g = 0; g < 4; ++g) {
      const int gi = wave * 4 + g;
      const half8 bf = *(const half8*)(slab + (gi * 16 + lrow) * RS + quad * 8);
      const f32x4 c0 = __builtin_amdgcn_mfma_f32_16x16x32_f16(a0, bf, bi0, 0, 0, 0);
      const f32x4 c1 = __builtin_amdgcn_mfma_f32_16x16x32_f16(a1, bf, bi1, 0, 0, 0);
      const float vn = v[gi * 16 + lrow];
      partial += (fmaxf(c0[0], 0.f) * u0.x + fmaxf(c0[1], 0.f) * u0.y +
                  fmaxf(c0[2], 0.f) * u0.z + fmaxf(c0[3], 0.f) * u0.w +
                  fmaxf(c1[0], 0.f) * u1.x + fmaxf(c1[1], 0.f) * u1.y +
                  fmaxf(c1[2], 0.f) * u1.z + fmaxf(c1[3], 0.f) * u1.w) * vn;
    }
#pragma unroll
    for (int off = 32; off > 0; off >>= 1) partial += __shfl_down(partial, off, 64);
    float* redp = (float*)slab;   // own-row bytes; safe after last slab read
    if (lane == 0) redp[wave * 20] = partial;  // wave0 -> slab[0], wave1 -> row 1 area
    __syncthreads();
    if (tid == 0) out[b] = redp[0] + redp[20] + cp[0];
  }
}

extern "C" void kernel_launch(void* const* d_in, const int* in_sizes, int n_in,
                              void* d_out, int out_size, void* d_ws, size_t ws_size,
                              hipStream_t stream) {
  const float* x      = (const float*)d_in[0];
  const float* adj    = (const float*)d_in[1];
  const float* W_lift = (const float*)d_in[2];
  const float* b_lift = (const float*)d_in[3];
  const float* W1     = (const float*)d_in[4];
  const float* b1     = (const float*)d_in[5];
  const float* W2     = (const float*)d_in[6];
  const float* b2     = (const float*)d_in[7];
  const float* W_ro   = (const float*)d_in[8];
  const float* b_ro   = (const float*)d_in[9];
  char* ws = (char*)d_ws;
  float* o = (float*)d_out;

  const int B = in_sizes[0] / (N * 3);   // 16384
  hipLaunchKernelGGL(prep, dim3(8), dim3(256), 0, stream,
                     adj, W1, W2, b2, W_ro, b_ro, ws);
  hipLaunchKernelGGL(gnn_mfma, dim3(B), dim3(128), 0, stream,
                     x, W_lift, b_lift, b1, b2, (const char*)ws, o);
}

// Round 6
// 232.483 us; speedup vs baseline: 1.0572x; 1.0572x over previous
//
#include <hip/hip_runtime.h>

// GNN surrogate — f16 MFMA, wave-per-batch, barrier-free (round-3 skeleton).
// New exact folds: lift absorbed into layer 0 (W1eff = W_lift@W1[0], K=3
// zero-padded to 32; b1eff = b_lift@W1[0]+b1[0]); biases ride in the MFMA
// C-operand; relu applied on packed f16 (v_pk_max_f16).
// Carried folds: v[j]=mean_i adj[i,j] absorbs layer-3 aggregation;
// u=W2[2]@W_ro, c=(b2[2]·W_ro)*sum(v)+b_ro absorbs the readout.

typedef _Float16 f16;
typedef __attribute__((ext_vector_type(8))) _Float16 half8;
typedef __attribute__((ext_vector_type(4))) _Float16 half4;
typedef __attribute__((ext_vector_type(2))) __fp16 fp16x2;   // cvt_pkrtz native
typedef __attribute__((ext_vector_type(4))) float f32x4;

namespace {
constexpr int N = 128, H = 32;
// ws byte layout
constexpr int WS_ADJF = 0;       // f16 [128][128] adj row-major      (32768 B)
constexpr int WS_W1T  = 32768;   // f16 [3][32][32]; l=0 slot = W1eff^T (K-padded)
constexpr int WS_W2T  = 38912;   // f16 [3][32][32] W2^T [fout][fmid]
constexpr int WS_V    = 45056;   // f32 [128] v[j] = mean_i adj[i][j]
constexpr int WS_U    = 45568;   // f32 [32]  u[k] = sum_c W2[2][k][c]*W_ro[c]
constexpr int WS_C    = 45696;   // f32 [1]
constexpr int WS_B1E  = 45760;   // f32 [32]  b1eff = b_lift@W1[0] + b1[0]
constexpr int RS = 40;    // bufH row stride, f16 (80 B)
constexpr int LS = 136;   // bufL row stride, f16 (272 B), overlaid on bufH
}

static __device__ __forceinline__ half4 pk4(float a, float b, float c, float d) {
  union { half4 v; fp16x2 h[2]; } u;
  u.h[0] = __builtin_amdgcn_cvt_pkrtz(a, b);
  u.h[1] = __builtin_amdgcn_cvt_pkrtz(c, d);
  return u.v;
}
static __device__ __forceinline__ half4 relu4(half4 v) {
  const half4 z = {};
  return __builtin_elementwise_max(v, z);   // v_pk_max_f16 x2
}

__global__ void prep(const float* __restrict__ adj,
                     const float* __restrict__ W_lift,
                     const float* __restrict__ b_lift,
                     const float* __restrict__ W1,
                     const float* __restrict__ b1,
                     const float* __restrict__ W2,
                     const float* __restrict__ b2,
                     const float* __restrict__ W_ro,
                     const float* __restrict__ b_ro,
                     char* __restrict__ ws) {
  const int tid = threadIdx.x;
  const int gid = blockIdx.x * 256 + tid;
  f16* adjf  = (f16*)(ws + WS_ADJF);
  f16* w1t   = (f16*)(ws + WS_W1T);
  f16* w2t   = (f16*)(ws + WS_W2T);
  float* v   = (float*)(ws + WS_V);
  float* u   = (float*)(ws + WS_U);
  float* cp  = (float*)(ws + WS_C);
  float* b1e = (float*)(ws + WS_B1E);

  for (int idx = gid; idx < N * N; idx += 2048) adjf[idx] = (f16)adj[idx];
  for (int idx = gid; idx < 3 * H * H; idx += 2048) {
    const int l = idx / (H * H), rem = idx % (H * H);
    const int fo = rem / H, fi = rem % H;
    if (l != 0) w1t[idx] = (f16)W1[l * H * H + fi * H + fo];  // l=0 slot: block 0
    w2t[idx] = (f16)W2[l * H * H + fi * H + fo];
  }
  if (blockIdx.x == 0) {
    // layer-0 folded weight: w1t[0][fo][k] = k<3 ? (W_lift@W1[0])[k][fo] : 0
    for (int idx = tid; idx < H * H; idx += 256) {
      const int fo = idx >> 5, k = idx & 31;
      float val = 0.f;
      if (k < 3) {
        for (int c = 0; c < H; ++c) val += W_lift[k * H + c] * W1[c * H + fo];
      }
      w1t[fo * H + k] = (f16)val;
    }
    __shared__ float sred[N];
    if (tid < N) {
      float s = 0.f;
      for (int i = 0; i < N; ++i) s += adj[i * N + tid];
      v[tid] = s * (1.0f / N);
      sred[tid] = s * (1.0f / N);
    }
    if (tid < H) {
      float s = b1[tid];
      for (int c = 0; c < H; ++c) s += b_lift[c] * W1[c * H + tid];
      b1e[tid] = s;
      float su = 0.f;
      for (int c = 0; c < H; ++c) su += W2[2 * H * H + tid * H + c] * W_ro[c];
      u[tid] = su;
    }
    __syncthreads();
    if (tid == 0) {
      float c2r = 0.f;
      for (int k = 0; k < H; ++k) c2r += b2[2 * H + k] * W_ro[k];
      float S = 0.f;
      for (int j = 0; j < N; ++j) S += sred[j];
      cp[0] = c2r * S + b_ro[0];
    }
  }
}

__global__ __launch_bounds__(256, 4)
void gnn_mfma(const float* __restrict__ x,
              const float* __restrict__ b1,
              const float* __restrict__ b2,
              const char* __restrict__ ws,
              float* __restrict__ out) {
  __shared__ f16 smem[4][N * RS];   // 40960 B -> 4 blocks/CU

  const f16* adjf  = (const f16*)(ws + WS_ADJF);
  const f16* w1t   = (const f16*)(ws + WS_W1T);
  const f16* w2t   = (const f16*)(ws + WS_W2T);
  const float* v   = (const float*)(ws + WS_V);
  const float* u   = (const float*)(ws + WS_U);
  const float* cp  = (const float*)(ws + WS_C);
  const float* b1e = (const float*)(ws + WS_B1E);

  const int tid  = threadIdx.x;
  const int wave = tid >> 6;
  const int lane = tid & 63;
  const int lrow = lane & 15;
  const int quad = lane >> 4;
  const int b    = blockIdx.x * 4 + wave;

  f16* buf = &smem[wave][0];
  const float* xb = x + (size_t)b * (N * 3);
  const f32x4 zero = {0.f, 0.f, 0.f, 0.f};

#pragma unroll
  for (int l = 0; l < 3; ++l) {
    // ---- Stage A: T = relu(W1^T · B + bias); l=0 takes B directly from x ----
    const f16* w1l = w1t + l * H * H;
    const half8 a0 = *(const half8*)(w1l + lrow * H + quad * 8);
    const half8 a1 = *(const half8*)(w1l + (16 + lrow) * H + quad * 8);
    const float* bsrc = (l == 0) ? (b1e + 0) : (b1 + l * H);
    const f32x4 bi0 = *(const f32x4*)(bsrc + quad * 4);
    const f32x4 bi1 = *(const f32x4*)(bsrc + 16 + quad * 4);

    if (l == 2) {
      // folded readout: out = sum relu(T2^T)·u·v + c
      const float4 u0 = *(const float4*)(u + quad * 4);
      const float4 u1 = *(const float4*)(u + 16 + quad * 4);
      float partial = 0.f;
#pragma unroll
      for (int g = 0; g < 8; ++g) {
        const half8 bf = *(const half8*)(buf + (g * 16 + lrow) * RS + quad * 8);
        const f32x4 c0 = __builtin_amdgcn_mfma_f32_16x16x32_f16(a0, bf, bi0, 0, 0, 0);
        const f32x4 c1 = __builtin_amdgcn_mfma_f32_16x16x32_f16(a1, bf, bi1, 0, 0, 0);
        const float vn = v[g * 16 + lrow];
        partial += (fmaxf(c0[0], 0.f) * u0.x + fmaxf(c0[1], 0.f) * u0.y +
                    fmaxf(c0[2], 0.f) * u0.z + fmaxf(c0[3], 0.f) * u0.w +
                    fmaxf(c1[0], 0.f) * u1.x + fmaxf(c1[1], 0.f) * u1.y +
                    fmaxf(c1[2], 0.f) * u1.z + fmaxf(c1[3], 0.f) * u1.w) * vn;
      }
#pragma unroll
      for (int off = 32; off > 0; off >>= 1) partial += __shfl_down(partial, off, 64);
      if (lane == 0) out[b] = partial + cp[0];
    } else {
#pragma unroll
      for (int g = 0; g < 8; ++g) {
        const int node = g * 16 + lrow;
        f16* row = buf + node * RS;
        half8 bf;
        if (l == 0) {
          union { half8 v8; fp16x2 p[4]; } bu;
          bu.v8 = (half8){};
          if (quad == 0) {
            const float x0 = xb[node * 3 + 0];
            const float x1 = xb[node * 3 + 1];
            const float x2 = xb[node * 3 + 2];
            bu.p[0] = __builtin_amdgcn_cvt_pkrtz(x0, x1);
            bu.p[1] = __builtin_amdgcn_cvt_pkrtz(x2, 0.f);
          }
          bf = bu.v8;
        } else {
          bf = *(const half8*)(row + quad * 8);   // read own row before write
        }
        const f32x4 c0 = __builtin_amdgcn_mfma_f32_16x16x32_f16(a0, bf, bi0, 0, 0, 0);
        const f32x4 c1 = __builtin_amdgcn_mfma_f32_16x16x32_f16(a1, bf, bi1, 0, 0, 0);
        *(half4*)(row + quad * 4)      = relu4(pk4(c0[0], c0[1], c0[2], c0[3]));
        *(half4*)(row + 16 + quad * 4) = relu4(pk4(c1[0], c1[1], c1[2], c1[3]));
      }

      // ---- Stage B: L = T·W2 + b2 -> bufL (L^T[fout][node]); preload all af
      // before any bufL write (overlay hazard; same-base alias preserves order)
      {
        const f16* w2l = w2t + l * H * H;
        const half8 wb0 = *(const half8*)(w2l + lrow * H + quad * 8);
        const half8 wb1 = *(const half8*)(w2l + (16 + lrow) * H + quad * 8);
        const float bs0 = b2[l * H + lrow];
        const float bs1 = b2[l * H + 16 + lrow];
        const f32x4 bib0 = {bs0, bs0, bs0, bs0};
        const f32x4 bib1 = {bs1, bs1, bs1, bs1};
        half8 af[8];
#pragma unroll
        for (int m = 0; m < 8; ++m)
          af[m] = *(const half8*)(buf + (m * 16 + lrow) * RS + quad * 8);
#pragma unroll
        for (int m = 0; m < 8; ++m) {
          const f32x4 d0 = __builtin_amdgcn_mfma_f32_16x16x32_f16(af[m], wb0, bib0, 0, 0, 0);
          const f32x4 d1 = __builtin_amdgcn_mfma_f32_16x16x32_f16(af[m], wb1, bib1, 0, 0, 0);
          const int ncol = m * 16 + quad * 4;
          *(half4*)(buf + lrow * LS + ncol)        = pk4(d0[0], d0[1], d0[2], d0[3]);
          *(half4*)(buf + (16 + lrow) * LS + ncol) = pk4(d1[0], d1[1], d1[2], d1[3]);
        }
      }

      // ---- Stage C: H' = adj·L; af2 fully preloaded, then only global adj
      // reads feed the MFMAs -> H' writes may clobber bufL freely.
      {
        half8 af2[2][4];
#pragma unroll
        for (int mt = 0; mt < 2; ++mt)
#pragma unroll
          for (int kt = 0; kt < 4; ++kt)
            af2[mt][kt] = *(const half8*)(buf + (mt * 16 + lrow) * LS + kt * 32 + quad * 8);
#pragma unroll
        for (int g = 0; g < 8; ++g) {
          f32x4 h0 = zero, h1 = zero;
#pragma unroll
          for (int kt = 0; kt < 4; ++kt) {
            const half8 bf = *(const half8*)(adjf + (g * 16 + lrow) * N + kt * 32 + quad * 8);
            h0 = __builtin_amdgcn_mfma_f32_16x16x32_f16(af2[0][kt], bf, h0, 0, 0, 0);
            h1 = __builtin_amdgcn_mfma_f32_16x16x32_f16(af2[1][kt], bf, h1, 0, 0, 0);
          }
          f16* row = buf + (g * 16 + lrow) * RS;
          *(half4*)(row + quad * 4)      = pk4(h0[0], h0[1], h0[2], h0[3]);
          *(half4*)(row + 16 + quad * 4) = pk4(h1[0], h1[1], h1[2], h1[3]);
        }
      }
    }
  }
}

extern "C" void kernel_launch(void* const* d_in, const int* in_sizes, int n_in,
                              void* d_out, int out_size, void* d_ws, size_t ws_size,
                              hipStream_t stream) {
  const float* x      = (const float*)d_in[0];
  const float* adj    = (const float*)d_in[1];
  const float* W_lift = (const float*)d_in[2];
  const float* b_lift = (const float*)d_in[3];
  const float* W1     = (const float*)d_in[4];
  const float* b1     = (const float*)d_in[5];
  const float* W2     = (const float*)d_in[6];
  const float* b2     = (const float*)d_in[7];
  const float* W_ro   = (const float*)d_in[8];
  const float* b_ro   = (const float*)d_in[9];
  char* ws = (char*)d_ws;
  float* o = (float*)d_out;

  const int B = in_sizes[0] / (N * 3);   // 16384
  hipLaunchKernelGGL(prep, dim3(8), dim3(256), 0, stream,
                     adj, W_lift, b_lift, W1, b1, W2, b2, W_ro, b_ro, ws);
  hipLaunchKernelGGL(gnn_mfma, dim3(B / 4), dim3(256), 0, stream,
                     x, b1, b2, (const char*)ws, o);
}

// Round 7
// 226.119 us; speedup vs baseline: 1.0869x; 1.0281x over previous
//
#include <hip/hip_runtime.h>

// GNN surrogate — f16 MFMA, wave-per-batch, barrier-free, 5-stage chain.
// Key fold (exact, uses adj row-normalization adj·1=1):
//   M_l = W2[l]@W1[l+1], c_l = b2[l]@W1[l+1]+b1[l+1]  collapses each layer's
//   second linear into the next layer's first -> chain L0,G0,L1,G1,L2.
// Layout rule: state is always the MFMA A-operand; C-frag writes go
// contiguously into the transposed buffer, which is the next stage's
// contiguous A-read. bufT (32x152) and bufP (128x40) overlay one 10 KB slab;
// every stage preloads all its A-fragments before its first overlaying write.
// Carried folds: v[j]=mean_i adj[i,j]; u=W2[2]@W_ro; cp=(b2[2]·W_ro)*sum(v)+b_ro.

typedef _Float16 f16;
typedef __attribute__((ext_vector_type(8))) _Float16 half8;
typedef __attribute__((ext_vector_type(4))) _Float16 half4;
typedef __attribute__((ext_vector_type(2))) __fp16 fp16x2;   // cvt_pkrtz native
typedef __attribute__((ext_vector_type(4))) float f32x4;

namespace {
constexpr int N = 128, H = 32;
// ws byte layout
constexpr int WS_ADJF = 0;       // f16 [128][128] adj row-major        (32768 B)
constexpr int WS_WFB  = 32768;   // f16 [3][2][64][8] B-frag-ordered Meff (6144 B)
constexpr int WS_BIAS = 38912;   // f32 [3][32] folded biases            (384 B)
constexpr int WS_V    = 39424;   // f32 [128] v[j]=mean_i adj[i][j]      (512 B)
constexpr int WS_U    = 39936;   // f32 [32]  u[k]=sum_c W2[2][k][c]W_ro (128 B)
constexpr int WS_C    = 40064;   // f32 [1]
constexpr int TS = 152;  // bufT row stride f16 (304 B = 16*19; step 12 mod 32 words)
constexpr int PS = 40;   // bufP row stride f16 (80 B = 16*5)
}

static __device__ __forceinline__ half4 pk4(float a, float b, float c, float d) {
  union { half4 v; fp16x2 h[2]; } u;
  u.h[0] = __builtin_amdgcn_cvt_pkrtz(a, b);
  u.h[1] = __builtin_amdgcn_cvt_pkrtz(c, d);
  return u.v;
}
static __device__ __forceinline__ half4 relu4(half4 v) {
  const half4 z = {};
  return __builtin_elementwise_max(v, z);   // v_pk_max_f16 x2
}

__global__ void prep(const float* __restrict__ adj,
                     const float* __restrict__ W_lift,
                     const float* __restrict__ b_lift,
                     const float* __restrict__ W1,
                     const float* __restrict__ b1,
                     const float* __restrict__ W2,
                     const float* __restrict__ b2,
                     const float* __restrict__ W_ro,
                     const float* __restrict__ b_ro,
                     char* __restrict__ ws) {
  const int tid = threadIdx.x;
  const int gid = blockIdx.x * 256 + tid;
  f16* adjf  = (f16*)(ws + WS_ADJF);
  f16* wfb   = (f16*)(ws + WS_WFB);
  float* bia = (float*)(ws + WS_BIAS);
  float* v   = (float*)(ws + WS_V);
  float* u   = (float*)(ws + WS_U);
  float* cp  = (float*)(ws + WS_C);

  for (int idx = gid; idx < N * N; idx += 2048) adjf[idx] = (f16)adj[idx];

  if (blockIdx.x == 0) {
    __shared__ float tmp[3][H][H];   // Meff_l[k][fo], fp32
    __shared__ float sred[N];
    for (int idx = tid; idx < 3 * H * H; idx += 256) {
      const int l = idx >> 10, rem = idx & 1023;
      const int k = rem >> 5, fo = rem & 31;
      float val = 0.f;
      if (l == 0) {
        if (k < 3) for (int c = 0; c < H; ++c) val += W_lift[k * H + c] * W1[c * H + fo];
      } else {
        const float* w2l = W2 + (l - 1) * H * H;
        const float* w1n = W1 + l * H * H;
        for (int c = 0; c < H; ++c) val += w2l[k * H + c] * w1n[c * H + fo];
      }
      tmp[l][k][fo] = val;
    }
    if (tid < N) {
      float s = 0.f;
      for (int i = 0; i < N; ++i) s += adj[i * N + tid];
      v[tid] = s * (1.0f / N);
      sred[tid] = s * (1.0f / N);
    }
    if (tid < H) {
      // bias0 = b_lift@W1[0]+b1[0]; bias_l = b2[l-1]@W1[l]+b1[l]
      float s0 = b1[tid], s1 = b1[H + tid], s2 = b1[2 * H + tid];
      for (int c = 0; c < H; ++c) {
        s0 += b_lift[c] * W1[c * H + tid];
        s1 += b2[c] * W1[H * H + c * H + tid];
        s2 += b2[H + c] * W1[2 * H * H + c * H + tid];
      }
      bia[tid] = s0; bia[H + tid] = s1; bia[2 * H + tid] = s2;
      float su = 0.f;
      for (int c = 0; c < H; ++c) su += W2[2 * H * H + tid * H + c] * W_ro[c];
      u[tid] = su;
    }
    __syncthreads();
    // B-fragment-ordered weights: wfb[l][t][lane=q*16+lr][j] = Meff_l[q*8+j][t*16+lr]
    for (int idx = tid; idx < 3 * 1024; idx += 256) {
      const int l = idx >> 10, rem = idx & 1023;
      const int t = rem >> 9, lane = (rem >> 3) & 63, j = rem & 7;
      const int q = lane >> 4, lr = lane & 15;
      wfb[idx] = (f16)tmp[l][q * 8 + j][t * 16 + lr];
    }
    if (tid == 0) {
      float c2r = 0.f;
      for (int k = 0; k < H; ++k) c2r += b2[2 * H + k] * W_ro[k];
      float S = 0.f;
      for (int j = 0; j < N; ++j) S += sred[j];
      cp[0] = c2r * S + b_ro[0];
    }
  }
}

__global__ __launch_bounds__(256, 4)
void gnn_mfma(const float* __restrict__ x,
              const char* __restrict__ ws,
              float* __restrict__ out) {
  __shared__ f16 smem[4][5120];   // 10240 B per wave; 40960 B -> 4 blocks/CU

  const f16* adjf  = (const f16*)(ws + WS_ADJF);
  const f16* wfb   = (const f16*)(ws + WS_WFB);
  const float* bia = (const float*)(ws + WS_BIAS);
  const float* v   = (const float*)(ws + WS_V);
  const float* u   = (const float*)(ws + WS_U);
  const float* cp  = (const float*)(ws + WS_C);

  const int tid  = threadIdx.x;
  const int wave = tid >> 6;
  const int lane = tid & 63;
  const int lrow = lane & 15;
  const int quad = lane >> 4;
  const int b    = blockIdx.x * 4 + wave;

  f16* slab = &smem[wave][0];
  const f32x4 zero = {0.f, 0.f, 0.f, 0.f};

  // ---- L0: T0 = relu(x · W1eff + b0)  -> bufT[fout][node] ----
  {
    const half8 w0 = *(const half8*)(wfb + 0 * 1024 + 0 * 512 + lane * 8);
    const half8 w1 = *(const half8*)(wfb + 0 * 1024 + 1 * 512 + lane * 8);
    const float bb0 = bia[lrow], bb1 = bia[16 + lrow];
    const f32x4 bi0 = {bb0, bb0, bb0, bb0};
    const f32x4 bi1 = {bb1, bb1, bb1, bb1};
#pragma unroll
    for (int g = 0; g < 8; ++g) {
      half8 ax = {};
      if (quad == 0) {
        const float* xr = x + ((size_t)b * N + g * 16 + lrow) * 3;
        union { half8 v8; fp16x2 p[4]; } xa;
        xa.v8 = (half8){};
        xa.p[0] = __builtin_amdgcn_cvt_pkrtz(xr[0], xr[1]);
        xa.p[1] = __builtin_amdgcn_cvt_pkrtz(xr[2], 0.f);
        ax = xa.v8;
      }
      const f32x4 c0 = __builtin_amdgcn_mfma_f32_16x16x32_f16(ax, w0, bi0, 0, 0, 0);
      const f32x4 c1 = __builtin_amdgcn_mfma_f32_16x16x32_f16(ax, w1, bi1, 0, 0, 0);
      *(half4*)(slab + lrow * TS + g * 16 + quad * 4)        = relu4(pk4(c0[0], c0[1], c0[2], c0[3]));
      *(half4*)(slab + (16 + lrow) * TS + g * 16 + quad * 4) = relu4(pk4(c1[0], c1[1], c1[2], c1[3]));
    }
  }

  // ---- G0/G1: P^T = T^T · adj^T  (K=128) -> bufP[node][feat]; and
  // ---- L1:    T1 = relu(P·M0 + c0)       -> bufT[fout][node]
#pragma unroll
  for (int l = 0; l < 2; ++l) {
    // Aggregation: preload all A-frags (bufT), then write bufP over the slab.
    {
      half8 aT[2][4];
#pragma unroll
      for (int t = 0; t < 2; ++t)
#pragma unroll
        for (int kt = 0; kt < 4; ++kt)
          aT[t][kt] = *(const half8*)(slab + (t * 16 + lrow) * TS + kt * 32 + quad * 8);
#pragma unroll
      for (int g = 0; g < 8; ++g) {
        f32x4 a0 = zero, a1 = zero;
#pragma unroll
        for (int kt = 0; kt < 4; ++kt) {
          const half8 bf = *(const half8*)(adjf + (g * 16 + lrow) * N + kt * 32 + quad * 8);
          a0 = __builtin_amdgcn_mfma_f32_16x16x32_f16(aT[0][kt], bf, a0, 0, 0, 0);
          a1 = __builtin_amdgcn_mfma_f32_16x16x32_f16(aT[1][kt], bf, a1, 0, 0, 0);
        }
        f16* prow = slab + (g * 16 + lrow) * PS;
        *(half4*)(prow + quad * 4)      = pk4(a0[0], a0[1], a0[2], a0[3]);
        *(half4*)(prow + 16 + quad * 4) = pk4(a1[0], a1[1], a1[2], a1[3]);
      }
    }
    if (l == 1) break;   // P1 stays in bufP for the readout stage

    // L1: preload all A-frags (bufP), then write bufT over the slab.
    {
      half8 af[8];
#pragma unroll
      for (int g = 0; g < 8; ++g)
        af[g] = *(const half8*)(slab + (g * 16 + lrow) * PS + quad * 8);
      const half8 w0 = *(const half8*)(wfb + 1 * 1024 + 0 * 512 + lane * 8);
      const half8 w1 = *(const half8*)(wfb + 1 * 1024 + 1 * 512 + lane * 8);
      const float bb0 = bia[H + lrow], bb1 = bia[H + 16 + lrow];
      const f32x4 bi0 = {bb0, bb0, bb0, bb0};
      const f32x4 bi1 = {bb1, bb1, bb1, bb1};
#pragma unroll
      for (int g = 0; g < 8; ++g) {
        const f32x4 c0 = __builtin_amdgcn_mfma_f32_16x16x32_f16(af[g], w0, bi0, 0, 0, 0);
        const f32x4 c1 = __builtin_amdgcn_mfma_f32_16x16x32_f16(af[g], w1, bi1, 0, 0, 0);
        *(half4*)(slab + lrow * TS + g * 16 + quad * 4)        = relu4(pk4(c0[0], c0[1], c0[2], c0[3]));
        *(half4*)(slab + (16 + lrow) * TS + g * 16 + quad * 4) = relu4(pk4(c1[0], c1[1], c1[2], c1[3]));
      }
    }
  }

  // ---- L2 + folded readout: out = sum relu(P1·M1 + c1)[n][f]·v[n]·u[f] + cp
  {
    const half8 w0 = *(const half8*)(wfb + 2 * 1024 + 0 * 512 + lane * 8);
    const half8 w1 = *(const half8*)(wfb + 2 * 1024 + 1 * 512 + lane * 8);
    const float bb0 = bia[2 * H + lrow], bb1 = bia[2 * H + 16 + lrow];
    const f32x4 bi0 = {bb0, bb0, bb0, bb0};
    const f32x4 bi1 = {bb1, bb1, bb1, bb1};
    const float u0 = u[lrow], u1 = u[16 + lrow];
    float partial = 0.f;
#pragma unroll
    for (int g = 0; g < 8; ++g) {
      const half8 af = *(const half8*)(slab + (g * 16 + lrow) * PS + quad * 8);
      const f32x4 c0 = __builtin_amdgcn_mfma_f32_16x16x32_f16(af, w0, bi0, 0, 0, 0);
      const f32x4 c1 = __builtin_amdgcn_mfma_f32_16x16x32_f16(af, w1, bi1, 0, 0, 0);
      const float4 vv = *(const float4*)(v + g * 16 + quad * 4);
      const float s0 = fmaxf(c0[0], 0.f) * vv.x + fmaxf(c0[1], 0.f) * vv.y +
                       fmaxf(c0[2], 0.f) * vv.z + fmaxf(c0[3], 0.f) * vv.w;
      const float s1 = fmaxf(c1[0], 0.f) * vv.x + fmaxf(c1[1], 0.f) * vv.y +
                       fmaxf(c1[2], 0.f) * vv.z + fmaxf(c1[3], 0.f) * vv.w;
      partial += s0 * u0 + s1 * u1;
    }
#pragma unroll
    for (int off = 32; off > 0; off >>= 1) partial += __shfl_down(partial, off, 64);
    if (lane == 0) out[b] = partial + cp[0];
  }
}

extern "C" void kernel_launch(void* const* d_in, const int* in_sizes, int n_in,
                              void* d_out, int out_size, void* d_ws, size_t ws_size,
                              hipStream_t stream) {
  const float* x      = (const float*)d_in[0];
  const float* adj    = (const float*)d_in[1];
  const float* W_lift = (const float*)d_in[2];
  const float* b_lift = (const float*)d_in[3];
  const float* W1     = (const float*)d_in[4];
  const float* b1     = (const float*)d_in[5];
  const float* W2     = (const float*)d_in[6];
  const float* b2     = (const float*)d_in[7];
  const float* W_ro   = (const float*)d_in[8];
  const float* b_ro   = (const float*)d_in[9];
  char* ws = (char*)d_ws;
  float* o = (float*)d_out;

  const int B = in_sizes[0] / (N * 3);   // 16384
  hipLaunchKernelGGL(prep, dim3(8), dim3(256), 0, stream,
                     adj, W_lift, b_lift, W1, b1, W2, b2, W_ro, b_ro, ws);
  hipLaunchKernelGGL(gnn_mfma, dim3(B / 4), dim3(256), 0, stream,
                     x, (const char*)ws, o);
}